// Round 8
// baseline (282.502 us; speedup 1.0000x reference)
//
#include <hip/hip_runtime.h>
#include <hip/hip_bf16.h>

#define N_NODES_C 100000
#define N_GRAPHS_C 64
#define FDIM 128
#define NPB 512                 // nodes per bucket
#define NBUCK 196               // ceil(100000/512)
#define SB 256                  // scatter blocks (K1/K2)

typedef _Float16 half8v __attribute__((ext_vector_type(8)));
typedef __attribute__((ext_vector_type(4))) float f32x4;

__device__ __forceinline__ unsigned short f2h(float f) {
    union { _Float16 h; unsigned short u; } v; v.h = (_Float16)f; return v.u;
}
__device__ __forceinline__ float h2flo(unsigned u) {
    union { unsigned short s; _Float16 h; } v; v.s = (unsigned short)u; return (float)v.h;
}
__device__ __forceinline__ float h2fhi(unsigned u) {
    union { unsigned short s; _Float16 h; } v; v.s = (unsigned short)(u >> 16); return (float)v.h;
}

// ================================================================ CSR build (bucketed, LDS atomics)
// K1: per-block bucket histogram
__global__ __launch_bounds__(256) void bucket_count(const int* __restrict__ tgt,
                                                    int* __restrict__ blockCnt, int E) {
    __shared__ int cnt[NBUCK];
    const int t = threadIdx.x;
    const int blk = blockIdx.x;
    if (t < NBUCK) cnt[t] = 0;
    __syncthreads();
    const int chunk = (E + SB - 1) / SB;
    const int base = blk * chunk;
    const int lim = min(E, base + chunk);
    for (int e = base + t; e < lim; e += 256) {
        atomicAdd(&cnt[tgt[e] >> 9], 1);
    }
    __syncthreads();
    if (t < NBUCK) blockCnt[t * SB + blk] = cnt[t];   // bucket-major
}

// scanA: per-bucket exclusive scan over its SB block counts (in place), total out
__global__ __launch_bounds__(256) void scanA(int* __restrict__ blockCnt,
                                             int* __restrict__ bucketTot) {
    __shared__ int s[256];
    const int t = threadIdx.x;
    const int b = blockIdx.x;
    int v = blockCnt[b * SB + t];
    s[t] = v;
    __syncthreads();
    for (int off = 1; off < 256; off <<= 1) {
        int u = (t >= off) ? s[t - off] : 0;
        __syncthreads();
        s[t] += u;
        __syncthreads();
    }
    blockCnt[b * SB + t] = s[t] - v;   // exclusive
    if (t == 255) bucketTot[b] = s[255];
}

// scanB: exclusive scan of 196 bucket totals -> bucketBase[0..196]
__global__ __launch_bounds__(256) void scanB(const int* __restrict__ bucketTot,
                                             int* __restrict__ bucketBase, int E) {
    __shared__ int s[256];
    const int t = threadIdx.x;
    int v = (t < NBUCK) ? bucketTot[t] : 0;
    s[t] = v;
    __syncthreads();
    for (int off = 1; off < 256; off <<= 1) {
        int u = (t >= off) ? s[t - off] : 0;
        __syncthreads();
        s[t] += u;
        __syncthreads();
    }
    if (t < NBUCK) bucketBase[t] = s[t] - v;
    if (t == 0) bucketBase[NBUCK] = E;
}

// K2: scatter (tgt,src) pairs into bucket-contiguous staging; rank via LDS atomics
__global__ __launch_bounds__(256) void bucket_scatter(const int* __restrict__ src,
                                                      const int* __restrict__ tgt,
                                                      const int* __restrict__ blockCnt,
                                                      const int* __restrict__ bucketBase,
                                                      uint2* __restrict__ staged, int E) {
    __shared__ int lcur[NBUCK];
    const int t = threadIdx.x;
    const int blk = blockIdx.x;
    if (t < NBUCK) lcur[t] = bucketBase[t] + blockCnt[t * SB + blk];
    __syncthreads();
    const int chunk = (E + SB - 1) / SB;
    const int base = blk * chunk;
    const int lim = min(E, base + chunk);
    for (int e = base + t; e < lim; e += 256) {
        int tv = tgt[e];
        int pos = atomicAdd(&lcur[tv >> 9], 1);
        uint2 p; p.x = (unsigned)tv; p.y = (unsigned)src[e];
        staged[pos] = p;
    }
}

// K3: per bucket: per-node degree (LDS), LDS scan -> rowstart+invd, LDS-cursor scatter -> csr
__global__ __launch_bounds__(256) void bucket_finalize(const uint2* __restrict__ staged,
                                                       const int* __restrict__ bucketBase,
                                                       int* __restrict__ rs,
                                                       float* __restrict__ invd,
                                                       int* __restrict__ csr, int N, int E) {
    __shared__ int dcnt[NPB];
    __shared__ int pref[NPB];
    __shared__ int ts[256];
    const int t = threadIdx.x;
    const int b = blockIdx.x;
    const int s = bucketBase[b];
    const int e = bucketBase[b + 1];
    const int nb0 = b * NPB;
    const int nn = min(NPB, N - nb0);   // nodes in this bucket

    dcnt[t] = 0; dcnt[t + 256] = 0;
    __syncthreads();
    for (int i = s + t; i < e; i += 256)
        atomicAdd(&dcnt[(int)staged[i].x - nb0], 1);
    __syncthreads();

    // exclusive scan of 512 via 256 threads
    int a0 = dcnt[2 * t], a1 = dcnt[2 * t + 1];
    ts[t] = a0 + a1;
    __syncthreads();
    for (int off = 1; off < 256; off <<= 1) {
        int u = (t >= off) ? ts[t - off] : 0;
        __syncthreads();
        ts[t] += u;
        __syncthreads();
    }
    int excl = (t > 0) ? ts[t - 1] : 0;
    pref[2 * t] = excl;
    pref[2 * t + 1] = excl + a0;
    __syncthreads();

    // write rowstart + inv_deg
    if (t < nn) {
        rs[nb0 + t] = s + pref[t];
        invd[nb0 + t] = 1.0f / (float)max(dcnt[t], 1);
    }
    int t2 = t + 256;
    if (t2 < nn) {
        rs[nb0 + t2] = s + pref[t2];
        invd[nb0 + t2] = 1.0f / (float)max(dcnt[t2], 1);
    }
    if (b == 0 && t == 0) rs[N] = E;
    __syncthreads();

    // reuse dcnt as running cursor = pref
    dcnt[t] = pref[t]; dcnt[t + 256] = pref[t + 256];
    __syncthreads();
    for (int i = s + t; i < e; i += 256) {
        uint2 p = staged[i];
        int r = atomicAdd(&dcnt[(int)p.x - nb0], 1);
        csr[s + r] = (int)p.y;
    }
}

// ================================================================ merged prep:
// [0, convBlocks)            : fp32->fp16 convert of x
// [convBlocks, +128)         : prep W1 -> wt1
// [+128, +256)               : prep W2 -> wt2
// last block                 : graph boundaries (batch sorted)
__device__ __forceinline__ void prep_w_body(const float* __restrict__ Wl,
                                            const float* __restrict__ Wr,
                                            unsigned short* __restrict__ outW, int id) {
    int c = id >> 9, i = id & 511;
    int l = i >> 3, e = i & 7;
    int khalf = c >> 5, nf = (c >> 2) & 7, ks4 = c & 3;
    int j = nf * 16 + (l & 15);
    int k = khalf * 128 + ks4 * 32 + ((l >> 4) << 3) + e;
    float w = (k < 128) ? Wl[k * 128 + j] : Wr[(k - 128) * 128 + j];
    outW[id] = f2h(w);
}

__global__ __launch_bounds__(256) void prep_all(const float* __restrict__ x,
                                                unsigned short* __restrict__ B0, int n8,
                                                const float* __restrict__ W1l,
                                                const float* __restrict__ W1r,
                                                unsigned short* __restrict__ wt1,
                                                const float* __restrict__ W2l,
                                                const float* __restrict__ W2r,
                                                unsigned short* __restrict__ wt2,
                                                const int* __restrict__ batch,
                                                int* __restrict__ gstart,
                                                float* __restrict__ gcnt, int nNodes,
                                                int convBlocks) {
    const int b = blockIdx.x;
    const int t = threadIdx.x;
    if (b < convBlocks) {
        int i = b * 256 + t;
        if (i < n8) {
            float4 v0 = *(const float4*)(x + (size_t)i * 8);
            float4 v1 = *(const float4*)(x + (size_t)i * 8 + 4);
            half8v o;
            o[0] = (_Float16)v0.x; o[1] = (_Float16)v0.y; o[2] = (_Float16)v0.z; o[3] = (_Float16)v0.w;
            o[4] = (_Float16)v1.x; o[5] = (_Float16)v1.y; o[6] = (_Float16)v1.z; o[7] = (_Float16)v1.w;
            *(half8v*)(B0 + (size_t)i * 8) = o;
        }
    } else if (b < convBlocks + 128) {
        prep_w_body(W1l, W1r, wt1, (b - convBlocks) * 256 + t);
    } else if (b < convBlocks + 256) {
        prep_w_body(W2l, W2r, wt2, (b - convBlocks - 128) * 256 + t);
    } else {
        if (t < 64) {
            int g = t;
            int lo = 0, hi = nNodes;
            while (lo < hi) { int m = (lo + hi) >> 1; if (batch[m] < g) lo = m + 1; else hi = m; }
            int lb = lo;
            lo = 0; hi = nNodes;
            while (lo < hi) { int m = (lo + hi) >> 1; if (batch[m] < g + 1) lo = m + 1; else hi = m; }
            gstart[g] = lb;
            gcnt[g] = (float)(lo - lb);
            if (g == 0) gstart[64] = nNodes;
        }
    }
}

// ---------------------------------------------------------------- CSR mean-aggregate (fp16 in/out)
// 16 lanes per node (4 nodes/wave); 16B row loads; unroll-4 + fully-parallel masked tail.
__device__ __forceinline__ void acc8h(float* a, half8v v) {
#pragma unroll
    for (int j = 0; j < 8; ++j) a[j] += (float)v[j];
}

__global__ __launch_bounds__(256) void agg_f16(const unsigned short* __restrict__ Xin,
                                               const int* __restrict__ csr,
                                               const int* __restrict__ rowstart,
                                               const float* __restrict__ invd,
                                               unsigned short* __restrict__ Agg, int N) {
    const int grp  = threadIdx.x >> 4;            // 0..15
    const int node = blockIdx.x * 16 + grp;
    if (node >= N) return;
    const int lane = threadIdx.x & 15;
    const int beg = rowstart[node];
    const int end = rowstart[node + 1];

    float a[8] = {0.f, 0.f, 0.f, 0.f, 0.f, 0.f, 0.f, 0.f};
    int e = beg;
    for (; e + 3 < end; e += 4) {
        int s0 = csr[e + 0];
        int s1 = csr[e + 1];
        int s2 = csr[e + 2];
        int s3 = csr[e + 3];
        half8v v0 = *(const half8v*)(Xin + ((size_t)s0 << 7) + lane * 8);
        half8v v1 = *(const half8v*)(Xin + ((size_t)s1 << 7) + lane * 8);
        half8v v2 = *(const half8v*)(Xin + ((size_t)s2 << 7) + lane * 8);
        half8v v3 = *(const half8v*)(Xin + ((size_t)s3 << 7) + lane * 8);
        acc8h(a, v0); acc8h(a, v1); acc8h(a, v2); acc8h(a, v3);
    }
    if (e < end) {
        // masked tail quad: all loads issued in parallel, adds predicated
        int i1 = min(e + 1, end - 1);
        int i2 = min(e + 2, end - 1);
        int s0 = csr[e];
        int s1 = csr[i1];
        int s2 = csr[i2];
        half8v v0 = *(const half8v*)(Xin + ((size_t)s0 << 7) + lane * 8);
        half8v v1 = *(const half8v*)(Xin + ((size_t)s1 << 7) + lane * 8);
        half8v v2 = *(const half8v*)(Xin + ((size_t)s2 << 7) + lane * 8);
        acc8h(a, v0);
        if (e + 1 < end) acc8h(a, v1);
        if (e + 2 < end) acc8h(a, v2);
    }

    float sc = invd[node];
    half8v o;
#pragma unroll
    for (int j = 0; j < 8; ++j) o[j] = (_Float16)(a[j] * sc);
    *(half8v*)(Agg + ((size_t)node << 7) + lane * 8) = o;
}

// ---------------------------------------------------------------- MFMA dual GEMM (fp16, no LDS)
// H[r,:] = relu( [Agg(r)|X(r)] @ W + b ), virtual K=256. 4 waves; wave owns 32 rows.
// W fragments read DIRECTLY from global (64 KB, L2-resident in every XCD) -> no
// barriers, no LDS -> occupancy is VGPR-bound, loads hidden by wave parallelism.
// Swapped operands => D^T: lane holds one node-row, 4 consecutive j-cols -> 8B stores.
__global__ __launch_bounds__(256) void gemm_mfma(const unsigned short* __restrict__ Agg,
                                                 const unsigned short* __restrict__ Xop,
                                                 const unsigned short* __restrict__ WtF,
                                                 const float* __restrict__ bias,
                                                 unsigned short* __restrict__ Hout, int N) {
    const int t = threadIdx.x;
    const int wave = t >> 6;
    const int l = t & 63;
    const int rw = blockIdx.x * 128 + wave * 32;
    const int lrow = l & 15;
    const int lk = (l >> 4) << 3;

    f32x4 acc[2][8];
#pragma unroll
    for (int m = 0; m < 2; ++m)
#pragma unroll
        for (int nf = 0; nf < 8; ++nf) acc[m][nf] = (f32x4)(0.f);

#pragma unroll
    for (int khalf = 0; khalf < 2; ++khalf) {
        const unsigned short* Asrc = khalf ? Xop : Agg;
#pragma unroll
        for (int ks4 = 0; ks4 < 4; ++ks4) {
            half8v af[2];
#pragma unroll
            for (int m = 0; m < 2; ++m) {
                int row = rw + m * 16 + lrow;
                if (row >= N) row = N - 1;  // clamp: only pollutes discarded rows
                af[m] = *(const half8v*)(Asrc + ((size_t)row << 7) + ks4 * 32 + lk);
            }
#pragma unroll
            for (int nf = 0; nf < 8; ++nf) {
                half8v bh = *(const half8v*)(WtF + ((khalf * 32 + nf * 4 + ks4) * 512) + l * 8);
#pragma unroll
                for (int m = 0; m < 2; ++m) {
                    acc[m][nf] = __builtin_amdgcn_mfma_f32_16x16x32_f16(bh, af[m], acc[m][nf], 0, 0, 0);
                }
            }
        }
    }

    const int jb = (l >> 4) << 2;
#pragma unroll
    for (int nf = 0; nf < 8; ++nf) {
        float4 bv = *(const float4*)&bias[nf * 16 + jb];
#pragma unroll
        for (int m = 0; m < 2; ++m) {
            int row = rw + m * 16 + (l & 15);
            if (row < N) {
                unsigned short h0 = f2h(fmaxf(acc[m][nf][0] + bv.x, 0.f));
                unsigned short h1 = f2h(fmaxf(acc[m][nf][1] + bv.y, 0.f));
                unsigned short h2 = f2h(fmaxf(acc[m][nf][2] + bv.z, 0.f));
                unsigned short h3 = f2h(fmaxf(acc[m][nf][3] + bv.w, 0.f));
                uint2 st;
                st.x = (unsigned)h0 | ((unsigned)h1 << 16);
                st.y = (unsigned)h2 | ((unsigned)h3 << 16);
                *(uint2*)(Hout + ((size_t)row << 7) + nf * 16 + jb) = st;
            }
        }
    }
}

// ---------------------------------------------------------------- segment-mean pool of agg3 & h2
__global__ __launch_bounds__(256) void pool_kernel(const unsigned short* __restrict__ A3,
                                                   const unsigned short* __restrict__ H2,
                                                   const int* __restrict__ gstart,
                                                   float* __restrict__ pa,
                                                   float* __restrict__ ph) {
    int g = blockIdx.x >> 2, q = blockIdx.x & 3;
    int s = gstart[g], e = gstart[g + 1];
    int len = e - s;
    int cs = s + (len * q) / 4;
    int ce = s + (len * (q + 1)) / 4;
    int t = threadIdx.x;
    int cp = t & 63;
    int rp = t >> 6;
    float sa0 = 0, sa1 = 0, sh0 = 0, sh1 = 0;
    for (int r = cs + rp; r < ce; r += 4) {
        unsigned ua = *(const unsigned*)(A3 + ((size_t)r << 7) + cp * 2);
        unsigned uh = *(const unsigned*)(H2 + ((size_t)r << 7) + cp * 2);
        sa0 += h2flo(ua); sa1 += h2fhi(ua);
        sh0 += h2flo(uh); sh1 += h2fhi(uh);
    }
    __shared__ float red[4][4][64];
    red[rp][0][cp] = sa0; red[rp][1][cp] = sa1;
    red[rp][2][cp] = sh0; red[rp][3][cp] = sh1;
    __syncthreads();
    if (rp == 0) {
        float ra0 = red[0][0][cp] + red[1][0][cp] + red[2][0][cp] + red[3][0][cp];
        float ra1 = red[0][1][cp] + red[1][1][cp] + red[2][1][cp] + red[3][1][cp];
        float rh0 = red[0][2][cp] + red[1][2][cp] + red[2][2][cp] + red[3][2][cp];
        float rh1 = red[0][3][cp] + red[1][3][cp] + red[2][3][cp] + red[3][3][cp];
        unsafeAtomicAdd(&pa[g * 128 + cp * 2 + 0], ra0);
        unsafeAtomicAdd(&pa[g * 128 + cp * 2 + 1], ra1);
        unsafeAtomicAdd(&ph[g * 128 + cp * 2 + 0], rh0);
        unsafeAtomicAdd(&ph[g * 128 + cp * 2 + 1], rh1);
    }
}

// ---------------------------------------------------------------- fused layer3 + readout (fp32)
__global__ __launch_bounds__(128) void final_fused(const float* __restrict__ pa,
                                                   const float* __restrict__ ph,
                                                   const float* __restrict__ gcnt,
                                                   const float* __restrict__ W3l,
                                                   const float* __restrict__ W3r,
                                                   const float* __restrict__ b3,
                                                   const float* __restrict__ Wout,
                                                   const float* __restrict__ bout,
                                                   float* __restrict__ out) {
    __shared__ float sA[FDIM], sH[FDIM], sT[FDIM];
    int g = blockIdx.x;
    int j = threadIdx.x;
    float inv = 1.0f / fmaxf(gcnt[g], 1.0f);
    sA[j] = pa[g * FDIM + j] * inv;
    sH[j] = ph[g * FDIM + j] * inv;
    __syncthreads();
    float acc = b3[j];
    for (int c = 0; c < FDIM; ++c)
        acc += sA[c] * W3l[c * FDIM + j] + sH[c] * W3r[c * FDIM + j];
    sT[j] = acc;
    __syncthreads();
    if (j < 10) {
        float o = bout[j];
        for (int c = 0; c < FDIM; ++c) o += sT[c] * Wout[c * 10 + j];
        out[g * 10 + j] = o;
    }
}

extern "C" void kernel_launch(void* const* d_in, const int* in_sizes, int n_in,
                              void* d_out, int out_size, void* d_ws, size_t ws_size,
                              hipStream_t stream) {
    const float* x     = (const float*)d_in[0];
    const int*   edge  = (const int*)d_in[1];
    const int*   batch = (const int*)d_in[2];
    const float* W1l = (const float*)d_in[3];
    const float* b1  = (const float*)d_in[4];
    const float* W1r = (const float*)d_in[5];
    const float* W2l = (const float*)d_in[6];
    const float* b2  = (const float*)d_in[7];
    const float* W2r = (const float*)d_in[8];
    const float* W3l = (const float*)d_in[9];
    const float* b3  = (const float*)d_in[10];
    const float* W3r = (const float*)d_in[11];
    const float* Wout = (const float*)d_in[12];
    const float* bout = (const float*)d_in[13];
    float* out = (float*)d_out;

    const int N = N_NODES_C;
    const int E = in_sizes[1] / 2;
    const int* src = edge;
    const int* tgt = edge + E;

    // ---- workspace layout
    char* ws = (char*)d_ws;
    size_t off = 0;
    auto carve = [&](size_t bytes) { char* p = ws + off; off += (bytes + 255) & ~(size_t)255; return p; };
    int*   rs   = (int*)carve((size_t)(N + 1) * 4);
    float* invd = (float*)carve((size_t)N * 4);
    int*   gstart = (int*)carve(65 * 4);
    float* gcnt = (float*)carve(64 * 4);
    float* pa   = (float*)carve((size_t)N_GRAPHS_C * FDIM * 4);
    float* ph   = (float*)carve((size_t)N_GRAPHS_C * FDIM * 4);
    unsigned short* wt1 = (unsigned short*)carve(32768 * 2);
    unsigned short* wt2 = (unsigned short*)carve(32768 * 2);
    int*   blockCnt  = (int*)carve((size_t)NBUCK * SB * 4);
    int*   bucketTot = (int*)carve(NBUCK * 4);
    int*   bucketBase = (int*)carve((NBUCK + 1) * 4);
    uint2* staged = (uint2*)carve((size_t)E * 8);
    int*   csr  = (int*)carve((size_t)E * 4);
    unsigned short* B0 = (unsigned short*)carve((size_t)N * FDIM * 2);
    unsigned short* B1 = (unsigned short*)carve((size_t)N * FDIM * 2);
    unsigned short* B2 = (unsigned short*)carve((size_t)N * FDIM * 2);

    // ---- zero init (pool accumulators only)
    hipMemsetAsync(pa, 0, (size_t)N_GRAPHS_C * FDIM * 4, stream);
    hipMemsetAsync(ph, 0, (size_t)N_GRAPHS_C * FDIM * 4, stream);

    // ---- merged prep: conv + both weight preps + graph boundaries
    const int n8 = N * FDIM / 8;
    const int convBlocks = (n8 + 255) / 256;
    prep_all<<<convBlocks + 256 + 1, 256, 0, stream>>>(x, B0, n8,
                                                       W1l, W1r, wt1, W2l, W2r, wt2,
                                                       batch, gstart, gcnt, N, convBlocks);

    // ---- CSR build: bucket count -> scans -> staged scatter -> finalize (rs, invd, csr)
    bucket_count<<<SB, 256, 0, stream>>>(tgt, blockCnt, E);
    scanA<<<NBUCK, 256, 0, stream>>>(blockCnt, bucketTot);
    scanB<<<1, 256, 0, stream>>>(bucketTot, bucketBase, E);
    bucket_scatter<<<SB, 256, 0, stream>>>(src, tgt, blockCnt, bucketBase, staged, E);
    bucket_finalize<<<NBUCK, 256, 0, stream>>>(staged, bucketBase, rs, invd, csr, N, E);

    const int aggGrid = (N + 15) / 16;
    const int gemmGrid = (N + 127) / 128;

    // ---- layer 1: agg1 -> B1 ; h1 = relu([B1|B0]@W1+b1) -> B2
    agg_f16<<<aggGrid, 256, 0, stream>>>(B0, csr, rs, invd, B1, N);
    gemm_mfma<<<gemmGrid, 256, 0, stream>>>(B1, B0, wt1, b1, B2, N);

    // ---- layer 2: agg2 -> B1 ; h2 = relu([B1|B2]@W2+b2) -> B0
    agg_f16<<<aggGrid, 256, 0, stream>>>(B2, csr, rs, invd, B1, N);
    gemm_mfma<<<gemmGrid, 256, 0, stream>>>(B1, B2, wt2, b2, B0, N);

    // ---- layer 3 folded through pooling: agg3 -> B1 ; pool agg3 & h2
    agg_f16<<<aggGrid, 256, 0, stream>>>(B0, csr, rs, invd, B1, N);
    pool_kernel<<<N_GRAPHS_C * 4, 256, 0, stream>>>(B1, B0, gstart, pa, ph);

    // ---- layer-3 GEMM (64 rows) + readout, full fp32
    final_fused<<<N_GRAPHS_C, 128, 0, stream>>>(pa, ph, gcnt, W3l, W3r, b3, Wout, bout, out);
}

// Round 9
// 237.867 us; speedup vs baseline: 1.1876x; 1.1876x over previous
//
#include <hip/hip_runtime.h>
#include <hip/hip_bf16.h>

#define N_NODES_C 100000
#define N_GRAPHS_C 64
#define FDIM 128
#define NPB 512                 // nodes per bucket
#define NBUCK 196               // ceil(100000/512)
#define SB 256                  // scatter blocks (K1/K2)

typedef _Float16 half8v __attribute__((ext_vector_type(8)));
typedef __attribute__((ext_vector_type(4))) float f32x4;

__device__ __forceinline__ unsigned short f2h(float f) {
    union { _Float16 h; unsigned short u; } v; v.h = (_Float16)f; return v.u;
}
__device__ __forceinline__ float h2flo(unsigned u) {
    union { unsigned short s; _Float16 h; } v; v.s = (unsigned short)u; return (float)v.h;
}
__device__ __forceinline__ float h2fhi(unsigned u) {
    union { unsigned short s; _Float16 h; } v; v.s = (unsigned short)(u >> 16); return (float)v.h;
}

// ================================================================ CSR build (bucketed, LDS atomics)
__global__ __launch_bounds__(256) void bucket_count(const int* __restrict__ tgt,
                                                    int* __restrict__ blockCnt, int E) {
    __shared__ int cnt[NBUCK];
    const int t = threadIdx.x;
    const int blk = blockIdx.x;
    if (t < NBUCK) cnt[t] = 0;
    __syncthreads();
    const int chunk = (E + SB - 1) / SB;
    const int base = blk * chunk;
    const int lim = min(E, base + chunk);
    for (int e = base + t; e < lim; e += 256) {
        atomicAdd(&cnt[tgt[e] >> 9], 1);
    }
    __syncthreads();
    if (t < NBUCK) blockCnt[t * SB + blk] = cnt[t];   // bucket-major
}

__global__ __launch_bounds__(256) void scanA(int* __restrict__ blockCnt,
                                             int* __restrict__ bucketTot) {
    __shared__ int s[256];
    const int t = threadIdx.x;
    const int b = blockIdx.x;
    int v = blockCnt[b * SB + t];
    s[t] = v;
    __syncthreads();
    for (int off = 1; off < 256; off <<= 1) {
        int u = (t >= off) ? s[t - off] : 0;
        __syncthreads();
        s[t] += u;
        __syncthreads();
    }
    blockCnt[b * SB + t] = s[t] - v;   // exclusive
    if (t == 255) bucketTot[b] = s[255];
}

__global__ __launch_bounds__(256) void scanB(const int* __restrict__ bucketTot,
                                             int* __restrict__ bucketBase, int E) {
    __shared__ int s[256];
    const int t = threadIdx.x;
    int v = (t < NBUCK) ? bucketTot[t] : 0;
    s[t] = v;
    __syncthreads();
    for (int off = 1; off < 256; off <<= 1) {
        int u = (t >= off) ? s[t - off] : 0;
        __syncthreads();
        s[t] += u;
        __syncthreads();
    }
    if (t < NBUCK) bucketBase[t] = s[t] - v;
    if (t == 0) bucketBase[NBUCK] = E;
}

__global__ __launch_bounds__(256) void bucket_scatter(const int* __restrict__ src,
                                                      const int* __restrict__ tgt,
                                                      const int* __restrict__ blockCnt,
                                                      const int* __restrict__ bucketBase,
                                                      uint2* __restrict__ staged, int E) {
    __shared__ int lcur[NBUCK];
    const int t = threadIdx.x;
    const int blk = blockIdx.x;
    if (t < NBUCK) lcur[t] = bucketBase[t] + blockCnt[t * SB + blk];
    __syncthreads();
    const int chunk = (E + SB - 1) / SB;
    const int base = blk * chunk;
    const int lim = min(E, base + chunk);
    for (int e = base + t; e < lim; e += 256) {
        int tv = tgt[e];
        int pos = atomicAdd(&lcur[tv >> 9], 1);
        uint2 p; p.x = (unsigned)tv; p.y = (unsigned)src[e];
        staged[pos] = p;
    }
}

__global__ __launch_bounds__(256) void bucket_finalize(const uint2* __restrict__ staged,
                                                       const int* __restrict__ bucketBase,
                                                       int* __restrict__ rs,
                                                       float* __restrict__ invd,
                                                       int* __restrict__ csr, int N, int E) {
    __shared__ int dcnt[NPB];
    __shared__ int pref[NPB];
    __shared__ int ts[256];
    const int t = threadIdx.x;
    const int b = blockIdx.x;
    const int s = bucketBase[b];
    const int e = bucketBase[b + 1];
    const int nb0 = b * NPB;
    const int nn = min(NPB, N - nb0);

    dcnt[t] = 0; dcnt[t + 256] = 0;
    __syncthreads();
    for (int i = s + t; i < e; i += 256)
        atomicAdd(&dcnt[(int)staged[i].x - nb0], 1);
    __syncthreads();

    int a0 = dcnt[2 * t], a1 = dcnt[2 * t + 1];
    ts[t] = a0 + a1;
    __syncthreads();
    for (int off = 1; off < 256; off <<= 1) {
        int u = (t >= off) ? ts[t - off] : 0;
        __syncthreads();
        ts[t] += u;
        __syncthreads();
    }
    int excl = (t > 0) ? ts[t - 1] : 0;
    pref[2 * t] = excl;
    pref[2 * t + 1] = excl + a0;
    __syncthreads();

    if (t < nn) {
        rs[nb0 + t] = s + pref[t];
        invd[nb0 + t] = 1.0f / (float)max(dcnt[t], 1);
    }
    int t2 = t + 256;
    if (t2 < nn) {
        rs[nb0 + t2] = s + pref[t2];
        invd[nb0 + t2] = 1.0f / (float)max(dcnt[t2], 1);
    }
    if (b == 0 && t == 0) rs[N] = E;
    __syncthreads();

    dcnt[t] = pref[t]; dcnt[t + 256] = pref[t + 256];
    __syncthreads();
    for (int i = s + t; i < e; i += 256) {
        uint2 p = staged[i];
        int r = atomicAdd(&dcnt[(int)p.x - nb0], 1);
        csr[s + r] = (int)p.y;
    }
}

// ================================================================ merged prep
__device__ __forceinline__ void prep_w_body(const float* __restrict__ Wl,
                                            const float* __restrict__ Wr,
                                            unsigned short* __restrict__ outW, int id) {
    int c = id >> 9, i = id & 511;
    int l = i >> 3, e = i & 7;
    int khalf = c >> 5, nf = (c >> 2) & 7, ks4 = c & 3;
    int j = nf * 16 + (l & 15);
    int k = khalf * 128 + ks4 * 32 + ((l >> 4) << 3) + e;
    float w = (k < 128) ? Wl[k * 128 + j] : Wr[(k - 128) * 128 + j];
    outW[id] = f2h(w);
}

__global__ __launch_bounds__(256) void prep_all(const float* __restrict__ x,
                                                unsigned short* __restrict__ B0, int n8,
                                                const float* __restrict__ W1l,
                                                const float* __restrict__ W1r,
                                                unsigned short* __restrict__ wt1,
                                                const float* __restrict__ W2l,
                                                const float* __restrict__ W2r,
                                                unsigned short* __restrict__ wt2,
                                                const int* __restrict__ batch,
                                                int* __restrict__ gstart,
                                                float* __restrict__ gcnt, int nNodes,
                                                int convBlocks) {
    const int b = blockIdx.x;
    const int t = threadIdx.x;
    if (b < convBlocks) {
        int i = b * 256 + t;
        if (i < n8) {
            float4 v0 = *(const float4*)(x + (size_t)i * 8);
            float4 v1 = *(const float4*)(x + (size_t)i * 8 + 4);
            half8v o;
            o[0] = (_Float16)v0.x; o[1] = (_Float16)v0.y; o[2] = (_Float16)v0.z; o[3] = (_Float16)v0.w;
            o[4] = (_Float16)v1.x; o[5] = (_Float16)v1.y; o[6] = (_Float16)v1.z; o[7] = (_Float16)v1.w;
            *(half8v*)(B0 + (size_t)i * 8) = o;
        }
    } else if (b < convBlocks + 128) {
        prep_w_body(W1l, W1r, wt1, (b - convBlocks) * 256 + t);
    } else if (b < convBlocks + 256) {
        prep_w_body(W2l, W2r, wt2, (b - convBlocks - 128) * 256 + t);
    } else {
        if (t < 64) {
            int g = t;
            int lo = 0, hi = nNodes;
            while (lo < hi) { int m = (lo + hi) >> 1; if (batch[m] < g) lo = m + 1; else hi = m; }
            int lb = lo;
            lo = 0; hi = nNodes;
            while (lo < hi) { int m = (lo + hi) >> 1; if (batch[m] < g + 1) lo = m + 1; else hi = m; }
            gstart[g] = lb;
            gcnt[g] = (float)(lo - lb);
            if (g == 0) gstart[64] = nNodes;
        }
    }
}

// ---------------------------------------------------------------- CSR mean-aggregate (fp16 in/out)
// 16 lanes/node; masked unroll-8 batches: 8 row-gathers in flight per node,
// out-of-range slots clamp to last edge (same line -> L1 hit) and are zeroed.
__device__ __forceinline__ void acc8h(float* a, half8v v) {
#pragma unroll
    for (int j = 0; j < 8; ++j) a[j] += (float)v[j];
}

__global__ __launch_bounds__(256) void agg_f16(const unsigned short* __restrict__ Xin,
                                               const int* __restrict__ csr,
                                               const int* __restrict__ rowstart,
                                               const float* __restrict__ invd,
                                               unsigned short* __restrict__ Agg, int N) {
    const int grp  = threadIdx.x >> 4;            // 0..15
    const int node = blockIdx.x * 16 + grp;
    if (node >= N) return;
    const int lane = threadIdx.x & 15;
    const int beg = rowstart[node];
    const int end = rowstart[node + 1];

    float a[8] = {0.f, 0.f, 0.f, 0.f, 0.f, 0.f, 0.f, 0.f};
    const half8v vzero = (half8v)(_Float16)0;
    for (int base = beg; base < end; base += 8) {
        const int cnt = end - base;               // >= 1
        int idx[8];
#pragma unroll
        for (int k = 0; k < 8; ++k) idx[k] = csr[min(base + k, end - 1)];
        half8v v[8];
#pragma unroll
        for (int k = 0; k < 8; ++k)
            v[k] = *(const half8v*)(Xin + ((size_t)idx[k] << 7) + lane * 8);
#pragma unroll
        for (int k = 0; k < 8; ++k) {
            half8v vv = (k < cnt) ? v[k] : vzero;
            acc8h(a, vv);
        }
    }

    float sc = invd[node];
    half8v o;
#pragma unroll
    for (int j = 0; j < 8; ++j) o[j] = (_Float16)(a[j] * sc);
    *(half8v*)(Agg + ((size_t)node << 7) + lane * 8) = o;
}

// ---------------------------------------------------------------- MFMA dual GEMM (fp16) — R7 known-good
// H[r,:] = relu( [Agg(r)|X(r)] @ W + b ), virtual K=256. 4 waves; wave owns 32 rows.
// W staged per-khalf in 32 KiB LDS. Swapped operands => D^T: lane holds one node-row,
// 4 consecutive j-cols -> 8B packed stores.
__global__ __launch_bounds__(256) void gemm_mfma(const unsigned short* __restrict__ Agg,
                                                 const unsigned short* __restrict__ Xop,
                                                 const unsigned short* __restrict__ WtF,
                                                 const float* __restrict__ bias,
                                                 unsigned short* __restrict__ Hout, int N) {
    __shared__ unsigned short wlds[32 * 512];   // 32 KiB: one khalf, fragment-ordered

    const int t = threadIdx.x;
    const int wave = t >> 6;
    const int l = t & 63;
    const int rw = blockIdx.x * 128 + wave * 32;
    const int lrow = l & 15;
    const int lk = (l >> 4) << 3;

    f32x4 acc[2][8];
#pragma unroll
    for (int m = 0; m < 2; ++m)
#pragma unroll
        for (int nf = 0; nf < 8; ++nf) acc[m][nf] = (f32x4)(0.f);

    for (int khalf = 0; khalf < 2; ++khalf) {
        if (khalf) __syncthreads();
#pragma unroll
        for (int rep = 0; rep < 8; ++rep) {
            int e = rep * 2048 + t * 8;
            *(half8v*)&wlds[e] = *(const half8v*)(WtF + khalf * 16384 + e);
        }
        __syncthreads();

        const unsigned short* Asrc = khalf ? Xop : Agg;
#pragma unroll
        for (int ks4 = 0; ks4 < 4; ++ks4) {
            half8v af[2];
#pragma unroll
            for (int m = 0; m < 2; ++m) {
                int row = rw + m * 16 + lrow;
                if (row >= N) row = N - 1;
                af[m] = *(const half8v*)(Asrc + ((size_t)row << 7) + ks4 * 32 + lk);
            }
#pragma unroll
            for (int nf = 0; nf < 8; ++nf) {
                half8v bh = *(const half8v*)&wlds[(nf * 4 + ks4) * 512 + l * 8];
#pragma unroll
                for (int m = 0; m < 2; ++m) {
                    acc[m][nf] = __builtin_amdgcn_mfma_f32_16x16x32_f16(bh, af[m], acc[m][nf], 0, 0, 0);
                }
            }
        }
    }

    const int jb = (l >> 4) << 2;
#pragma unroll
    for (int nf = 0; nf < 8; ++nf) {
        float4 bv = *(const float4*)&bias[nf * 16 + jb];
#pragma unroll
        for (int m = 0; m < 2; ++m) {
            int row = rw + m * 16 + (l & 15);
            if (row < N) {
                unsigned short h0 = f2h(fmaxf(acc[m][nf][0] + bv.x, 0.f));
                unsigned short h1 = f2h(fmaxf(acc[m][nf][1] + bv.y, 0.f));
                unsigned short h2 = f2h(fmaxf(acc[m][nf][2] + bv.z, 0.f));
                unsigned short h3 = f2h(fmaxf(acc[m][nf][3] + bv.w, 0.f));
                uint2 st;
                st.x = (unsigned)h0 | ((unsigned)h1 << 16);
                st.y = (unsigned)h2 | ((unsigned)h3 << 16);
                *(uint2*)(Hout + ((size_t)row << 7) + nf * 16 + jb) = st;
            }
        }
    }
}

// ---------------------------------------------------------------- segment-mean pool of agg3 & h2
__global__ __launch_bounds__(256) void pool_kernel(const unsigned short* __restrict__ A3,
                                                   const unsigned short* __restrict__ H2,
                                                   const int* __restrict__ gstart,
                                                   float* __restrict__ pa,
                                                   float* __restrict__ ph) {
    int g = blockIdx.x >> 2, q = blockIdx.x & 3;
    int s = gstart[g], e = gstart[g + 1];
    int len = e - s;
    int cs = s + (len * q) / 4;
    int ce = s + (len * (q + 1)) / 4;
    int t = threadIdx.x;
    int cp = t & 63;
    int rp = t >> 6;
    float sa0 = 0, sa1 = 0, sh0 = 0, sh1 = 0;
    for (int r = cs + rp; r < ce; r += 4) {
        unsigned ua = *(const unsigned*)(A3 + ((size_t)r << 7) + cp * 2);
        unsigned uh = *(const unsigned*)(H2 + ((size_t)r << 7) + cp * 2);
        sa0 += h2flo(ua); sa1 += h2fhi(ua);
        sh0 += h2flo(uh); sh1 += h2fhi(uh);
    }
    __shared__ float red[4][4][64];
    red[rp][0][cp] = sa0; red[rp][1][cp] = sa1;
    red[rp][2][cp] = sh0; red[rp][3][cp] = sh1;
    __syncthreads();
    if (rp == 0) {
        float ra0 = red[0][0][cp] + red[1][0][cp] + red[2][0][cp] + red[3][0][cp];
        float ra1 = red[0][1][cp] + red[1][1][cp] + red[2][1][cp] + red[3][1][cp];
        float rh0 = red[0][2][cp] + red[1][2][cp] + red[2][2][cp] + red[3][2][cp];
        float rh1 = red[0][3][cp] + red[1][3][cp] + red[2][3][cp] + red[3][3][cp];
        unsafeAtomicAdd(&pa[g * 128 + cp * 2 + 0], ra0);
        unsafeAtomicAdd(&pa[g * 128 + cp * 2 + 1], ra1);
        unsafeAtomicAdd(&ph[g * 128 + cp * 2 + 0], rh0);
        unsafeAtomicAdd(&ph[g * 128 + cp * 2 + 1], rh1);
    }
}

// ---------------------------------------------------------------- fused layer3 + readout (fp32)
__global__ __launch_bounds__(128) void final_fused(const float* __restrict__ pa,
                                                   const float* __restrict__ ph,
                                                   const float* __restrict__ gcnt,
                                                   const float* __restrict__ W3l,
                                                   const float* __restrict__ W3r,
                                                   const float* __restrict__ b3,
                                                   const float* __restrict__ Wout,
                                                   const float* __restrict__ bout,
                                                   float* __restrict__ out) {
    __shared__ float sA[FDIM], sH[FDIM], sT[FDIM];
    int g = blockIdx.x;
    int j = threadIdx.x;
    float inv = 1.0f / fmaxf(gcnt[g], 1.0f);
    sA[j] = pa[g * FDIM + j] * inv;
    sH[j] = ph[g * FDIM + j] * inv;
    __syncthreads();
    float acc = b3[j];
    for (int c = 0; c < FDIM; ++c)
        acc += sA[c] * W3l[c * FDIM + j] + sH[c] * W3r[c * FDIM + j];
    sT[j] = acc;
    __syncthreads();
    if (j < 10) {
        float o = bout[j];
        for (int c = 0; c < FDIM; ++c) o += sT[c] * Wout[c * 10 + j];
        out[g * 10 + j] = o;
    }
}

extern "C" void kernel_launch(void* const* d_in, const int* in_sizes, int n_in,
                              void* d_out, int out_size, void* d_ws, size_t ws_size,
                              hipStream_t stream) {
    const float* x     = (const float*)d_in[0];
    const int*   edge  = (const int*)d_in[1];
    const int*   batch = (const int*)d_in[2];
    const float* W1l = (const float*)d_in[3];
    const float* b1  = (const float*)d_in[4];
    const float* W1r = (const float*)d_in[5];
    const float* W2l = (const float*)d_in[6];
    const float* b2  = (const float*)d_in[7];
    const float* W2r = (const float*)d_in[8];
    const float* W3l = (const float*)d_in[9];
    const float* b3  = (const float*)d_in[10];
    const float* W3r = (const float*)d_in[11];
    const float* Wout = (const float*)d_in[12];
    const float* bout = (const float*)d_in[13];
    float* out = (float*)d_out;

    const int N = N_NODES_C;
    const int E = in_sizes[1] / 2;
    const int* src = edge;
    const int* tgt = edge + E;

    // ---- workspace layout
    char* ws = (char*)d_ws;
    size_t off = 0;
    auto carve = [&](size_t bytes) { char* p = ws + off; off += (bytes + 255) & ~(size_t)255; return p; };
    int*   rs   = (int*)carve((size_t)(N + 1) * 4);
    float* invd = (float*)carve((size_t)N * 4);
    int*   gstart = (int*)carve(65 * 4);
    float* gcnt = (float*)carve(64 * 4);
    float* pa   = (float*)carve((size_t)N_GRAPHS_C * FDIM * 4);
    float* ph   = (float*)carve((size_t)N_GRAPHS_C * FDIM * 4);
    unsigned short* wt1 = (unsigned short*)carve(32768 * 2);
    unsigned short* wt2 = (unsigned short*)carve(32768 * 2);
    int*   blockCnt  = (int*)carve((size_t)NBUCK * SB * 4);
    int*   bucketTot = (int*)carve(NBUCK * 4);
    int*   bucketBase = (int*)carve((NBUCK + 1) * 4);
    uint2* staged = (uint2*)carve((size_t)E * 8);
    int*   csr  = (int*)carve((size_t)E * 4);
    unsigned short* B0 = (unsigned short*)carve((size_t)N * FDIM * 2);
    unsigned short* B1 = (unsigned short*)carve((size_t)N * FDIM * 2);
    unsigned short* B2 = (unsigned short*)carve((size_t)N * FDIM * 2);

    // ---- zero init (pool accumulators only)
    hipMemsetAsync(pa, 0, (size_t)N_GRAPHS_C * FDIM * 4, stream);
    hipMemsetAsync(ph, 0, (size_t)N_GRAPHS_C * FDIM * 4, stream);

    // ---- merged prep: conv + both weight preps + graph boundaries
    const int n8 = N * FDIM / 8;
    const int convBlocks = (n8 + 255) / 256;
    prep_all<<<convBlocks + 256 + 1, 256, 0, stream>>>(x, B0, n8,
                                                       W1l, W1r, wt1, W2l, W2r, wt2,
                                                       batch, gstart, gcnt, N, convBlocks);

    // ---- CSR build: bucket count -> scans -> staged scatter -> finalize (rs, invd, csr)
    bucket_count<<<SB, 256, 0, stream>>>(tgt, blockCnt, E);
    scanA<<<NBUCK, 256, 0, stream>>>(blockCnt, bucketTot);
    scanB<<<1, 256, 0, stream>>>(bucketTot, bucketBase, E);
    bucket_scatter<<<SB, 256, 0, stream>>>(src, tgt, blockCnt, bucketBase, staged, E);
    bucket_finalize<<<NBUCK, 256, 0, stream>>>(staged, bucketBase, rs, invd, csr, N, E);

    const int aggGrid = (N + 15) / 16;
    const int gemmGrid = (N + 127) / 128;

    // ---- layer 1: agg1 -> B1 ; h1 = relu([B1|B0]@W1+b1) -> B2
    agg_f16<<<aggGrid, 256, 0, stream>>>(B0, csr, rs, invd, B1, N);
    gemm_mfma<<<gemmGrid, 256, 0, stream>>>(B1, B0, wt1, b1, B2, N);

    // ---- layer 2: agg2 -> B1 ; h2 = relu([B1|B2]@W2+b2) -> B0
    agg_f16<<<aggGrid, 256, 0, stream>>>(B2, csr, rs, invd, B1, N);
    gemm_mfma<<<gemmGrid, 256, 0, stream>>>(B1, B2, wt2, b2, B0, N);

    // ---- layer 3 folded through pooling: agg3 -> B1 ; pool agg3 & h2
    agg_f16<<<aggGrid, 256, 0, stream>>>(B0, csr, rs, invd, B1, N);
    pool_kernel<<<N_GRAPHS_C * 4, 256, 0, stream>>>(B1, B0, gstart, pa, ph);

    // ---- layer-3 GEMM (64 rows) + readout, full fp32
    final_fused<<<N_GRAPHS_C, 128, 0, stream>>>(pa, ph, gcnt, W3l, W3r, b3, Wout, bout, out);
}

// Round 10
// 218.438 us; speedup vs baseline: 1.2933x; 1.0889x over previous
//
#include <hip/hip_runtime.h>
#include <hip/hip_bf16.h>

#define N_NODES_C 100000
#define N_GRAPHS_C 64
#define FDIM 128
#define NPB 512                 // nodes per bucket
#define NBUCK 196               // ceil(100000/512)
#define SB 256                  // scatter blocks (K1/K2)

typedef _Float16 half8v __attribute__((ext_vector_type(8)));
typedef __attribute__((ext_vector_type(4))) float f32x4;

__device__ __forceinline__ unsigned short f2h(float f) {
    union { _Float16 h; unsigned short u; } v; v.h = (_Float16)f; return v.u;
}

__device__ __forceinline__ void acc8h(float* a, half8v v) {
#pragma unroll
    for (int j = 0; j < 8; ++j) a[j] += (float)v[j];
}

// ================================================================ CSR build (bucketed, LDS atomics)
__global__ __launch_bounds__(256) void bucket_count(const int* __restrict__ tgt,
                                                    int* __restrict__ blockCnt, int E) {
    __shared__ int cnt[NBUCK];
    const int t = threadIdx.x;
    const int blk = blockIdx.x;
    if (t < NBUCK) cnt[t] = 0;
    __syncthreads();
    const int chunk = (E + SB - 1) / SB;
    const int base = blk * chunk;
    const int lim = min(E, base + chunk);
    for (int e = base + t; e < lim; e += 256) {
        atomicAdd(&cnt[tgt[e] >> 9], 1);
    }
    __syncthreads();
    if (t < NBUCK) blockCnt[t * SB + blk] = cnt[t];   // bucket-major
}

// scanA (per-bucket exclusive scan of block counts) + scanB (bucket bases) fused:
// the last block to finish runs scanB inline (threadfence + device-scope atomic).
__global__ __launch_bounds__(256) void scanAB(int* __restrict__ blockCnt,
                                              int* __restrict__ bucketTot,
                                              int* __restrict__ bucketBase,
                                              int* __restrict__ done, int E) {
    __shared__ int s[256];
    __shared__ int lastFlag;
    const int t = threadIdx.x;
    const int b = blockIdx.x;
    int v = blockCnt[b * SB + t];
    s[t] = v;
    __syncthreads();
    for (int off = 1; off < 256; off <<= 1) {
        int u = (t >= off) ? s[t - off] : 0;
        __syncthreads();
        s[t] += u;
        __syncthreads();
    }
    blockCnt[b * SB + t] = s[t] - v;   // exclusive
    if (t == 255) bucketTot[b] = s[255];

    __threadfence();                    // publish bucketTot/blockCnt (release)
    if (t == 0) {
        int prev = atomicAdd(done, 1);
        lastFlag = (prev == (int)gridDim.x - 1);
    }
    __syncthreads();
    if (!lastFlag) return;
    __threadfence();                    // acquire: see all other blocks' writes

    int v2 = (t < NBUCK) ? bucketTot[t] : 0;
    s[t] = v2;
    __syncthreads();
    for (int off = 1; off < 256; off <<= 1) {
        int u = (t >= off) ? s[t - off] : 0;
        __syncthreads();
        s[t] += u;
        __syncthreads();
    }
    if (t < NBUCK) bucketBase[t] = s[t] - v2;
    if (t == 0) bucketBase[NBUCK] = E;
}

__global__ __launch_bounds__(256) void bucket_scatter(const int* __restrict__ src,
                                                      const int* __restrict__ tgt,
                                                      const int* __restrict__ blockCnt,
                                                      const int* __restrict__ bucketBase,
                                                      uint2* __restrict__ staged, int E) {
    __shared__ int lcur[NBUCK];
    const int t = threadIdx.x;
    const int blk = blockIdx.x;
    if (t < NBUCK) lcur[t] = bucketBase[t] + blockCnt[t * SB + blk];
    __syncthreads();
    const int chunk = (E + SB - 1) / SB;
    const int base = blk * chunk;
    const int lim = min(E, base + chunk);
    for (int e = base + t; e < lim; e += 256) {
        int tv = tgt[e];
        int pos = atomicAdd(&lcur[tv >> 9], 1);
        uint2 p; p.x = (unsigned)tv; p.y = (unsigned)src[e];
        staged[pos] = p;
    }
}

__global__ __launch_bounds__(256) void bucket_finalize(const uint2* __restrict__ staged,
                                                       const int* __restrict__ bucketBase,
                                                       int* __restrict__ rs,
                                                       float* __restrict__ invd,
                                                       int* __restrict__ csr, int N, int E) {
    __shared__ int dcnt[NPB];
    __shared__ int pref[NPB];
    __shared__ int ts[256];
    const int t = threadIdx.x;
    const int b = blockIdx.x;
    const int s = bucketBase[b];
    const int e = bucketBase[b + 1];
    const int nb0 = b * NPB;
    const int nn = min(NPB, N - nb0);

    dcnt[t] = 0; dcnt[t + 256] = 0;
    __syncthreads();
    for (int i = s + t; i < e; i += 256)
        atomicAdd(&dcnt[(int)staged[i].x - nb0], 1);
    __syncthreads();

    int a0 = dcnt[2 * t], a1 = dcnt[2 * t + 1];
    ts[t] = a0 + a1;
    __syncthreads();
    for (int off = 1; off < 256; off <<= 1) {
        int u = (t >= off) ? ts[t - off] : 0;
        __syncthreads();
        ts[t] += u;
        __syncthreads();
    }
    int excl = (t > 0) ? ts[t - 1] : 0;
    pref[2 * t] = excl;
    pref[2 * t + 1] = excl + a0;
    __syncthreads();

    if (t < nn) {
        rs[nb0 + t] = s + pref[t];
        invd[nb0 + t] = 1.0f / (float)max(dcnt[t], 1);
    }
    int t2 = t + 256;
    if (t2 < nn) {
        rs[nb0 + t2] = s + pref[t2];
        invd[nb0 + t2] = 1.0f / (float)max(dcnt[t2], 1);
    }
    if (b == 0 && t == 0) rs[N] = E;
    __syncthreads();

    dcnt[t] = pref[t]; dcnt[t + 256] = pref[t + 256];
    __syncthreads();
    for (int i = s + t; i < e; i += 256) {
        uint2 p = staged[i];
        int r = atomicAdd(&dcnt[(int)p.x - nb0], 1);
        csr[s + r] = (int)p.y;
    }
}

// ================================================================ merged prep
// [0, convBlocks): x fp32->fp16 ; [+128): W1 ; [+128): W2 ; last: graph bounds + zero pa/ph + done=0
__device__ __forceinline__ void prep_w_body(const float* __restrict__ Wl,
                                            const float* __restrict__ Wr,
                                            unsigned short* __restrict__ outW, int id) {
    int c = id >> 9, i = id & 511;
    int l = i >> 3, e = i & 7;
    int khalf = c >> 5, nf = (c >> 2) & 7, ks4 = c & 3;
    int j = nf * 16 + (l & 15);
    int k = khalf * 128 + ks4 * 32 + ((l >> 4) << 3) + e;
    float w = (k < 128) ? Wl[k * 128 + j] : Wr[(k - 128) * 128 + j];
    outW[id] = f2h(w);
}

__global__ __launch_bounds__(256) void prep_all(const float* __restrict__ x,
                                                unsigned short* __restrict__ B0, int n8,
                                                const float* __restrict__ W1l,
                                                const float* __restrict__ W1r,
                                                unsigned short* __restrict__ wt1,
                                                const float* __restrict__ W2l,
                                                const float* __restrict__ W2r,
                                                unsigned short* __restrict__ wt2,
                                                const int* __restrict__ batch,
                                                int* __restrict__ gstart,
                                                float* __restrict__ gcnt,
                                                float* __restrict__ pa,
                                                float* __restrict__ ph,
                                                int* __restrict__ done,
                                                int nNodes, int convBlocks) {
    const int b = blockIdx.x;
    const int t = threadIdx.x;
    if (b < convBlocks) {
        int i = b * 256 + t;
        if (i < n8) {
            float4 v0 = *(const float4*)(x + (size_t)i * 8);
            float4 v1 = *(const float4*)(x + (size_t)i * 8 + 4);
            half8v o;
            o[0] = (_Float16)v0.x; o[1] = (_Float16)v0.y; o[2] = (_Float16)v0.z; o[3] = (_Float16)v0.w;
            o[4] = (_Float16)v1.x; o[5] = (_Float16)v1.y; o[6] = (_Float16)v1.z; o[7] = (_Float16)v1.w;
            *(half8v*)(B0 + (size_t)i * 8) = o;
        }
    } else if (b < convBlocks + 128) {
        prep_w_body(W1l, W1r, wt1, (b - convBlocks) * 256 + t);
    } else if (b < convBlocks + 256) {
        prep_w_body(W2l, W2r, wt2, (b - convBlocks - 128) * 256 + t);
    } else {
        if (t < 64) {
            int g = t;
            int lo = 0, hi = nNodes;
            while (lo < hi) { int m = (lo + hi) >> 1; if (batch[m] < g) lo = m + 1; else hi = m; }
            int lb = lo;
            lo = 0; hi = nNodes;
            while (lo < hi) { int m = (lo + hi) >> 1; if (batch[m] < g + 1) lo = m + 1; else hi = m; }
            gstart[g] = lb;
            gcnt[g] = (float)(lo - lb);
            if (g == 0) gstart[64] = nNodes;
        }
        for (int i = t; i < N_GRAPHS_C * FDIM; i += 256) { pa[i] = 0.f; ph[i] = 0.f; }
        if (t == 64) *done = 0;
    }
}

// ================================================================ fused SAGE layer (agg + dual GEMM)
// Block = 128 nodes, 512 thr (8 waves). Phase 1: 32 groups x 16 lanes aggregate into
// XOR-swizzled LDS tile. Phase 2: MFMA khalf0 (A=agg tile from LDS) + khalf1 (A=X from
// global), W staged per-khalf in 32 KiB LDS. Swapped operands => lane owns one node-row.
__global__ __launch_bounds__(512) void sage_layer(const unsigned short* __restrict__ Xin,
                                                  const unsigned short* __restrict__ WtF,
                                                  const float* __restrict__ bias,
                                                  const int* __restrict__ csr,
                                                  const int* __restrict__ rs,
                                                  const float* __restrict__ invd,
                                                  unsigned short* __restrict__ Hout, int N) {
    __shared__ unsigned short atile[128 * 128];   // 32 KiB agg tile, 16B-chunk XOR swizzle
    __shared__ unsigned short wlds[32 * 512];     // 32 KiB, one khalf of W

    const int t = threadIdx.x;
    const int r0 = blockIdx.x * 128;

    // stage W khalf0 (consumed after the barrier below)
#pragma unroll
    for (int rep = 0; rep < 4; ++rep) {
        int e = rep * 4096 + t * 8;
        *(half8v*)&wlds[e] = *(const half8v*)(WtF + e);
    }

    // ---- aggregate phase: 32 groups x 16 lanes; 4 nodes per group
    {
        const int grp = t >> 4, lane = t & 15;
        const half8v vzero = (half8v)(_Float16)0;
#pragma unroll
        for (int it = 0; it < 4; ++it) {
            const int row = it * 32 + grp;        // 0..127
            const int node = r0 + row;
            float a[8] = {0.f, 0.f, 0.f, 0.f, 0.f, 0.f, 0.f, 0.f};
            if (node < N) {
                const int beg = rs[node], end = rs[node + 1];
                for (int base = beg; base < end; base += 8) {
                    const int cnt = end - base;   // >= 1
                    int idx[8];
#pragma unroll
                    for (int k = 0; k < 8; ++k) idx[k] = csr[min(base + k, end - 1)];
                    half8v v[8];
#pragma unroll
                    for (int k = 0; k < 8; ++k)
                        v[k] = *(const half8v*)(Xin + ((size_t)idx[k] << 7) + lane * 8);
#pragma unroll
                    for (int k = 0; k < 8; ++k) {
                        half8v vv = (k < cnt) ? v[k] : vzero;
                        acc8h(a, vv);
                    }
                }
                float sc = invd[node];
#pragma unroll
                for (int j = 0; j < 8; ++j) a[j] *= sc;
            }
            half8v o;
#pragma unroll
            for (int j = 0; j < 8; ++j) o[j] = (_Float16)a[j];
            const int chunk = lane ^ (row & 7);   // 16B-chunk XOR swizzle
            *(half8v*)&atile[row * 128 + chunk * 8] = o;
        }
    }
    __syncthreads();

    const int wave = t >> 6, l = t & 63;
    const int trow = wave * 16 + (l & 15);        // row within tile / D^T node-row
    const int lk = (l >> 4) << 3;

    f32x4 acc[8];
#pragma unroll
    for (int nf = 0; nf < 8; ++nf) acc[nf] = (f32x4)(0.f);

    // khalf0: A = agg tile (LDS, swizzled), W = wlds
#pragma unroll
    for (int ks4 = 0; ks4 < 4; ++ks4) {
        const int chunk = (ks4 * 4 + (l >> 4)) ^ (trow & 7);
        half8v af = *(const half8v*)&atile[trow * 128 + chunk * 8];
#pragma unroll
        for (int nf = 0; nf < 8; ++nf) {
            half8v bh = *(const half8v*)&wlds[(nf * 4 + ks4) * 512 + l * 8];
            acc[nf] = __builtin_amdgcn_mfma_f32_16x16x32_f16(bh, af, acc[nf], 0, 0, 0);
        }
    }
    __syncthreads();
    // stage W khalf1
#pragma unroll
    for (int rep = 0; rep < 4; ++rep) {
        int e = rep * 4096 + t * 8;
        *(half8v*)&wlds[e] = *(const half8v*)(WtF + 16384 + e);
    }
    __syncthreads();

    // khalf1: A = X rows from global
    {
        int row = r0 + trow;
        if (row >= N) row = N - 1;                // clamp: only pollutes discarded rows
#pragma unroll
        for (int ks4 = 0; ks4 < 4; ++ks4) {
            half8v af = *(const half8v*)(Xin + ((size_t)row << 7) + ks4 * 32 + lk);
#pragma unroll
            for (int nf = 0; nf < 8; ++nf) {
                half8v bh = *(const half8v*)&wlds[(nf * 4 + ks4) * 512 + l * 8];
                acc[nf] = __builtin_amdgcn_mfma_f32_16x16x32_f16(bh, af, acc[nf], 0, 0, 0);
            }
        }
    }

    // epilogue: lane's node-row = r0+trow; j = nf*16 + (l>>4)*4 + r ; relu + 8B stores
    const int jb = (l >> 4) << 2;
    const int orow = r0 + trow;
    if (orow < N) {
#pragma unroll
        for (int nf = 0; nf < 8; ++nf) {
            float4 bv = *(const float4*)&bias[nf * 16 + jb];
            unsigned short h0 = f2h(fmaxf(acc[nf][0] + bv.x, 0.f));
            unsigned short h1 = f2h(fmaxf(acc[nf][1] + bv.y, 0.f));
            unsigned short h2 = f2h(fmaxf(acc[nf][2] + bv.z, 0.f));
            unsigned short h3 = f2h(fmaxf(acc[nf][3] + bv.w, 0.f));
            uint2 st;
            st.x = (unsigned)h0 | ((unsigned)h1 << 16);
            st.y = (unsigned)h2 | ((unsigned)h3 << 16);
            *(uint2*)(Hout + ((size_t)orow << 7) + nf * 16 + jb) = st;
        }
    }
}

// ================================================================ fused agg3 + mean pool
// pa[g] += sum_{nodes i in slice} invd[i] * sum_{j in N(i)} h2[j]   (fp32, pre-rounding)
// ph[g] += sum_{nodes i in slice} h2[i]
// 16 blocks per graph; 256 thr = 16 groups x 16 lanes; LDS-reduce; 128x2 atomics/block.
__global__ __launch_bounds__(256) void agg3_pool(const unsigned short* __restrict__ H2,
                                                 const int* __restrict__ csr,
                                                 const int* __restrict__ rs,
                                                 const float* __restrict__ invd,
                                                 const int* __restrict__ gstart,
                                                 float* __restrict__ pa,
                                                 float* __restrict__ ph) {
    const int g = blockIdx.x >> 4;
    const int q = blockIdx.x & 15;
    const int s = gstart[g], e = gstart[g + 1];
    const int len = e - s;
    const int cs = s + (len * q) / 16;
    const int ce = s + (len * (q + 1)) / 16;
    const int t = threadIdx.x;
    const int grp = t >> 4, lane = t & 15;

    float aacc[8] = {0.f, 0.f, 0.f, 0.f, 0.f, 0.f, 0.f, 0.f};
    float hacc[8] = {0.f, 0.f, 0.f, 0.f, 0.f, 0.f, 0.f, 0.f};
    const half8v vzero = (half8v)(_Float16)0;

    for (int node = cs + grp; node < ce; node += 16) {
        const int beg = rs[node], end = rs[node + 1];
        float a[8] = {0.f, 0.f, 0.f, 0.f, 0.f, 0.f, 0.f, 0.f};
        for (int base = beg; base < end; base += 8) {
            const int cnt = end - base;
            int idx[8];
#pragma unroll
            for (int k = 0; k < 8; ++k) idx[k] = csr[min(base + k, end - 1)];
            half8v v[8];
#pragma unroll
            for (int k = 0; k < 8; ++k)
                v[k] = *(const half8v*)(H2 + ((size_t)idx[k] << 7) + lane * 8);
#pragma unroll
            for (int k = 0; k < 8; ++k) {
                half8v vv = (k < cnt) ? v[k] : vzero;
                acc8h(a, vv);
            }
        }
        const float sc = invd[node];
#pragma unroll
        for (int j = 0; j < 8; ++j) aacc[j] += a[j] * sc;
        half8v own = *(const half8v*)(H2 + ((size_t)node << 7) + lane * 8);
        acc8h(hacc, own);
    }

    __shared__ float red[16][128];
#pragma unroll
    for (int j = 0; j < 8; ++j) red[grp][lane * 8 + j] = aacc[j];
    __syncthreads();
    if (t < 128) {
        float sum = 0.f;
#pragma unroll
        for (int k = 0; k < 16; ++k) sum += red[k][t];
        unsafeAtomicAdd(&pa[g * 128 + t], sum);
    }
    __syncthreads();
#pragma unroll
    for (int j = 0; j < 8; ++j) red[grp][lane * 8 + j] = hacc[j];
    __syncthreads();
    if (t < 128) {
        float sum = 0.f;
#pragma unroll
        for (int k = 0; k < 16; ++k) sum += red[k][t];
        unsafeAtomicAdd(&ph[g * 128 + t], sum);
    }
}

// ---------------------------------------------------------------- fused layer3 + readout (fp32)
__global__ __launch_bounds__(128) void final_fused(const float* __restrict__ pa,
                                                   const float* __restrict__ ph,
                                                   const float* __restrict__ gcnt,
                                                   const float* __restrict__ W3l,
                                                   const float* __restrict__ W3r,
                                                   const float* __restrict__ b3,
                                                   const float* __restrict__ Wout,
                                                   const float* __restrict__ bout,
                                                   float* __restrict__ out) {
    __shared__ float sA[FDIM], sH[FDIM], sT[FDIM];
    int g = blockIdx.x;
    int j = threadIdx.x;
    float inv = 1.0f / fmaxf(gcnt[g], 1.0f);
    sA[j] = pa[g * FDIM + j] * inv;
    sH[j] = ph[g * FDIM + j] * inv;
    __syncthreads();
    float acc = b3[j];
    for (int c = 0; c < FDIM; ++c)
        acc += sA[c] * W3l[c * FDIM + j] + sH[c] * W3r[c * FDIM + j];
    sT[j] = acc;
    __syncthreads();
    if (j < 10) {
        float o = bout[j];
        for (int c = 0; c < FDIM; ++c) o += sT[c] * Wout[c * 10 + j];
        out[g * 10 + j] = o;
    }
}

extern "C" void kernel_launch(void* const* d_in, const int* in_sizes, int n_in,
                              void* d_out, int out_size, void* d_ws, size_t ws_size,
                              hipStream_t stream) {
    const float* x     = (const float*)d_in[0];
    const int*   edge  = (const int*)d_in[1];
    const int*   batch = (const int*)d_in[2];
    const float* W1l = (const float*)d_in[3];
    const float* b1  = (const float*)d_in[4];
    const float* W1r = (const float*)d_in[5];
    const float* W2l = (const float*)d_in[6];
    const float* b2  = (const float*)d_in[7];
    const float* W2r = (const float*)d_in[8];
    const float* W3l = (const float*)d_in[9];
    const float* b3  = (const float*)d_in[10];
    const float* W3r = (const float*)d_in[11];
    const float* Wout = (const float*)d_in[12];
    const float* bout = (const float*)d_in[13];
    float* out = (float*)d_out;

    const int N = N_NODES_C;
    const int E = in_sizes[1] / 2;
    const int* src = edge;
    const int* tgt = edge + E;

    // ---- workspace layout
    char* ws = (char*)d_ws;
    size_t off = 0;
    auto carve = [&](size_t bytes) { char* p = ws + off; off += (bytes + 255) & ~(size_t)255; return p; };
    int*   rs   = (int*)carve((size_t)(N + 1) * 4);
    float* invd = (float*)carve((size_t)N * 4);
    int*   gstart = (int*)carve(65 * 4);
    float* gcnt = (float*)carve(64 * 4);
    float* pa   = (float*)carve((size_t)N_GRAPHS_C * FDIM * 4);
    float* ph   = (float*)carve((size_t)N_GRAPHS_C * FDIM * 4);
    int*   done = (int*)carve(256);
    unsigned short* wt1 = (unsigned short*)carve(32768 * 2);
    unsigned short* wt2 = (unsigned short*)carve(32768 * 2);
    int*   blockCnt  = (int*)carve((size_t)NBUCK * SB * 4);
    int*   bucketTot = (int*)carve(NBUCK * 4);
    int*   bucketBase = (int*)carve((NBUCK + 1) * 4);
    uint2* staged = (uint2*)carve((size_t)E * 8);
    int*   csr  = (int*)carve((size_t)E * 4);
    unsigned short* B0 = (unsigned short*)carve((size_t)N * FDIM * 2);
    unsigned short* B2 = (unsigned short*)carve((size_t)N * FDIM * 2);

    // ---- merged prep: conv + weight preps + graph bounds + zero pa/ph + done=0
    const int n8 = N * FDIM / 8;
    const int convBlocks = (n8 + 255) / 256;
    prep_all<<<convBlocks + 257, 256, 0, stream>>>(x, B0, n8,
                                                   W1l, W1r, wt1, W2l, W2r, wt2,
                                                   batch, gstart, gcnt, pa, ph, done,
                                                   N, convBlocks);

    // ---- CSR build
    bucket_count<<<SB, 256, 0, stream>>>(tgt, blockCnt, E);
    scanAB<<<NBUCK, 256, 0, stream>>>(blockCnt, bucketTot, bucketBase, done, E);
    bucket_scatter<<<SB, 256, 0, stream>>>(src, tgt, blockCnt, bucketBase, staged, E);
    bucket_finalize<<<NBUCK, 256, 0, stream>>>(staged, bucketBase, rs, invd, csr, N, E);

    const int layerGrid = (N + 127) / 128;

    // ---- layer 1 fused: h1 = relu([mean_N(x)|x]@W1+b1) -> B2
    sage_layer<<<layerGrid, 512, 0, stream>>>(B0, wt1, b1, csr, rs, invd, B2, N);
    // ---- layer 2 fused: h2 = relu([mean_N(h1)|h1]@W2+b2) -> B0
    sage_layer<<<layerGrid, 512, 0, stream>>>(B2, wt2, b2, csr, rs, invd, B0, N);

    // ---- layer 3 aggregation folded directly into pooling (no materialization)
    agg3_pool<<<N_GRAPHS_C * 16, 256, 0, stream>>>(B0, csr, rs, invd, gstart, pa, ph);

    // ---- layer-3 GEMM (64 rows) + readout, full fp32
    final_fused<<<N_GRAPHS_C, 128, 0, stream>>>(pa, ph, gcnt, W3l, W3r, b3, Wout, bout, out);
}